// Round 1
// baseline (182.734 us; speedup 1.0000x reference)
//
#include <hip/hip_runtime.h>
#include <math.h>

static constexpr int B_ = 32;
static constexpr int RES_ = 50;
#define NORMF (1.0f/(2.0f*0.05f*0.05f + 1e-8f))

// ---------------------------------------------------------------------------
// K0: Gaussian tables. gx[i][c] = exp(-(x_i - c*h)^2 * nf), i<50, c<F.
//     gt is the transposed copy [c][i] for the second contraction.
// ---------------------------------------------------------------------------
__global__ void k_tables(float* __restrict__ gx, float* __restrict__ gt, int F) {
    int i = blockIdx.x;                       // 0..49
    float xi = (float)i * (1.0f / 49.0f);
    float hstep = 1.0f / (float)(F - 1);
    for (int c = threadIdx.x; c < F; c += blockDim.x) {
        float t = xi - (float)c * hstep;
        float g = __expf(-t * t * NORMF);
        gx[i * F + c] = g;
        gt[c * RES_ + i] = g;
    }
}

// ---------------------------------------------------------------------------
// K1: bilinear splat of w = min(|d-b|,10)^2 onto a fine F x F grid.
//     Each block owns one (batch, y-segment of 64 bins, point-chunk) and a
//     private F x 64 fp32 tile in LDS (<= 64 KB). Full-tile store at the end.
// ---------------------------------------------------------------------------
__global__ void __launch_bounds__(256) k_splat(const float2* __restrict__ pts,
                                               float* __restrict__ outp,
                                               int N, int P, int F, int directHS) {
    extern __shared__ float tile[];           // F * 64 floats
    const int SEG = F >> 6;
    int id = blockIdx.x;
    int chunk = id % P;
    int seg = (id / P) % SEG;
    int b = id / (P * SEG);
    int tileN = F * 64;
    for (int t = threadIdx.x; t < tileN; t += 256) tile[t] = 0.0f;
    __syncthreads();

    int ppc = N / P;
    const float2* p = pts + (size_t)b * N + (size_t)chunk * ppc;
    float scale = (float)(F - 1);
    int ylo = seg * 64;

    for (int t = threadIdx.x; t < ppc; t += 256) {
        float2 bd = p[t];
        float pers = fminf(fabsf(bd.y - bd.x), 10.0f);
        float w = pers * pers;
        float fx = fminf(fmaxf(bd.x * scale, 0.0f), scale);
        float fy = fminf(fmaxf(bd.y * scale, 0.0f), scale);
        int ix = (int)fx; if (ix > F - 2) ix = F - 2;
        int iy = (int)fy; if (iy > F - 2) iy = F - 2;
        float ax = fx - (float)ix;
        float ay = fy - (float)iy;
        int cy0 = iy - ylo;
        int cy1 = cy0 + 1;
        float wx0 = w * (1.0f - ax), wx1 = w * ax;
        if (cy0 >= 0 && cy0 < 64) {
            float fy0 = 1.0f - ay;
            atomicAdd(&tile[(ix << 6) + cy0], wx0 * fy0);
            atomicAdd(&tile[((ix + 1) << 6) + cy0], wx1 * fy0);
        }
        if (cy1 >= 0 && cy1 < 64) {
            atomicAdd(&tile[(ix << 6) + cy1], wx0 * ay);
            atomicAdd(&tile[((ix + 1) << 6) + cy1], wx1 * ay);
        }
    }
    __syncthreads();

    if (directHS) {
        // write straight into Hsum[b][cx][seg*64 + cyL]  (P == 1 path)
        float* dst = outp + (size_t)b * F * F + ylo;
        for (int t = threadIdx.x; t < tileN; t += 256) {
            int cx = t >> 6, cyL = t & 63;
            dst[(size_t)cx * F + cyL] = tile[t];
        }
    } else {
        // partial layout [blockId][cx][cyL]
        float* dst = outp + (size_t)id * tileN;
        for (int t = threadIdx.x; t < tileN; t += 256) dst[t] = tile[t];
    }
}

// ---------------------------------------------------------------------------
// K2a: sum P point-chunk partials -> Hsum[b][cx][cy]
// ---------------------------------------------------------------------------
__global__ void k_sum(const float* __restrict__ partials, float* __restrict__ hs,
                      int P, int F) {
    const int SEG = F >> 6;
    size_t tid = (size_t)blockIdx.x * 256 + threadIdx.x;
    size_t total = (size_t)B_ * F * F;
    if (tid >= total) return;
    int cyL = (int)(tid & 63);
    size_t r = tid >> 6;
    int cx = (int)(r % F); r /= F;
    int seg = (int)(r % SEG);
    int b = (int)(r / SEG);
    const float* base = partials + ((size_t)(b * SEG + seg) * P) * ((size_t)F * 64)
                                 + (size_t)cx * 64 + cyL;
    float s = 0.0f;
    for (int c = 0; c < P; c++) s += base[(size_t)c * F * 64];
    hs[(size_t)b * F * F + (size_t)cx * F + seg * 64 + cyL] = s;
}

// ---------------------------------------------------------------------------
// K2b: T[b][i][cy] = sum_cx Gx[i][cx] * H[b][cx][cy]
//      block = (b, 64-wide cy chunk); 256 thr = 64 cy x 4 i-subsets.
// ---------------------------------------------------------------------------
__global__ void __launch_bounds__(256) k_conv1(const float* __restrict__ gx,
                                               const float* __restrict__ hs,
                                               float* __restrict__ T, int F) {
    extern __shared__ float sgx[];            // 50 * F floats
    int nG = RES_ * F;
    for (int t = threadIdx.x; t < nG; t += 256) sgx[t] = gx[t];
    __syncthreads();

    int nCh = F >> 6;
    int cyChunk = blockIdx.x % nCh;
    int b = blockIdx.x / nCh;
    int tx = threadIdx.x & 63;
    int ty = threadIdx.x >> 6;                // 0..3
    int cy = (cyChunk << 6) + tx;

    float acc[13];
#pragma unroll
    for (int k = 0; k < 13; k++) acc[k] = 0.0f;

    const float* hsb = hs + (size_t)b * F * F + cy;
    for (int cx = 0; cx < F; cx++) {
        float h = hsb[(size_t)cx * F];
#pragma unroll
        for (int k = 0; k < 13; k++) {
            int i = ty + 4 * k;
            if (i < RES_) acc[k] += sgx[i * F + cx] * h;
        }
    }
#pragma unroll
    for (int k = 0; k < 13; k++) {
        int i = ty + 4 * k;
        if (i < RES_) T[((size_t)b * RES_ + i) * F + cy] = acc[k];
    }
}

// ---------------------------------------------------------------------------
// K2c: out[b][i][j] = sum_cy T[b][i][cy] * GT[cy][j]
// ---------------------------------------------------------------------------
__global__ void __launch_bounds__(64) k_conv2(const float* __restrict__ T,
                                              const float* __restrict__ gt,
                                              float* __restrict__ out, int F) {
    int i = blockIdx.x % RES_;
    int b = blockIdx.x / RES_;
    __shared__ float sT[256];
    const float* Trow = T + ((size_t)b * RES_ + i) * F;
    for (int t = threadIdx.x; t < F; t += 64) sT[t] = Trow[t];
    __syncthreads();
    int j = threadIdx.x;
    if (j < RES_) {
        float acc = 0.0f;
        for (int cy = 0; cy < F; cy++) acc += sT[cy] * gt[cy * RES_ + j];
        out[((size_t)b * RES_ + i) * RES_ + j] = acc;
    }
}

// ---------------------------------------------------------------------------
extern "C" void kernel_launch(void* const* d_in, const int* in_sizes, int n_in,
                              void* d_out, int out_size, void* d_ws, size_t ws_size,
                              hipStream_t stream) {
    const float2* pts = (const float2*)d_in[0];
    int N = in_sizes[0] / (2 * B_);           // 65536
    float* ws = (float*)d_ws;
    float* out = (float*)d_out;

    // pick fine-grid F and point-chunk count P to fit workspace
    size_t wsf = ws_size / 4;                 // floats available
    int F = 0, P = 0;
    const int Fs[3] = {256, 128, 64};
    const int Ps[3] = {4, 2, 1};
    for (int fi = 0; fi < 3 && F == 0; fi++) {
        for (int pi = 0; pi < 3; pi++) {
            int f = Fs[fi], p = Ps[pi];
            size_t need = (size_t)2 * RES_ * f          // tables
                        + (size_t)B_ * f * f            // Hsum
                        + (size_t)B_ * RES_ * f         // T
                        + (p > 1 ? (size_t)B_ * p * f * f : 0);  // partials
            if (need <= wsf) { F = f; P = p; break; }
        }
    }
    if (F == 0) { F = 64; P = 1; }            // last resort (~0.8 MB)

    int SEG = F / 64;
    size_t gxo = 0;
    size_t gto = gxo + (size_t)RES_ * F;
    size_t hso = gto + (size_t)RES_ * F;
    size_t To  = hso + (size_t)B_ * F * F;
    size_t po  = To  + (size_t)B_ * RES_ * F;
    float* gx = ws + gxo;
    float* gt = ws + gto;
    float* hs = ws + hso;
    float* T  = ws + To;
    float* partials = ws + po;

    k_tables<<<RES_, 256, 0, stream>>>(gx, gt, F);

    int grid1 = B_ * SEG * P;
    size_t lds1 = (size_t)F * 64 * 4;         // <= 64 KB
    k_splat<<<grid1, 256, lds1, stream>>>(pts, (P > 1) ? partials : hs,
                                          N, P, F, (P == 1) ? 1 : 0);

    if (P > 1) {
        size_t total = (size_t)B_ * F * F;
        k_sum<<<(int)((total + 255) / 256), 256, 0, stream>>>(partials, hs, P, F);
    }

    k_conv1<<<B_ * (F / 64), 256, (size_t)RES_ * F * 4, stream>>>(gx, hs, T, F);
    k_conv2<<<B_ * RES_, 64, 0, stream>>>(T, gt, out, F);
}

// Round 2
// 133.842 us; speedup vs baseline: 1.3653x; 1.3653x over previous
//
#include <hip/hip_runtime.h>
#include <math.h>

static constexpr int B_ = 32;
static constexpr int RES_ = 50;
static constexpr int F_ = 256;              // fine grid
#define NF (1.0f/(2.0f*0.05f*0.05f + 1e-8f))

// ---------------------------------------------------------------------------
// K0: Gaussian table in padded-slot layout gtab[c][slot], slot = w*16+k maps
//     to grid row i = w*13+k (k<13, i<50); other slots are 0.
//     gtab[c*64+slot] = exp(-(x_i - c*h)^2 * nf).   256*64 floats = 64 KB.
// ---------------------------------------------------------------------------
__global__ void k_tables(float* __restrict__ gtab) {
    int c = blockIdx.x;                     // 0..255
    int s = threadIdx.x;                    // 0..63
    int w = s >> 4, k = s & 15;
    int i = w * 13 + k;
    float v = 0.0f;
    if (k < 13 && i < RES_) {
        float t = (float)i * (1.0f / 49.0f) - (float)c * (1.0f / 255.0f);
        v = __expf(-t * t * NF);
    }
    gtab[c * 64 + s] = v;
}

// ---------------------------------------------------------------------------
// K1: bilinear splat, P=1. Block = (seg, b); blockIdx = seg*32 + b so the 4
//     seg-blocks of a batch are 32 apart (same XCD under %8 round-robin) and
//     share the batch's points in that XCD's L2. 64 KB private LDS tile,
//     written directly to hs[b][cx][cy].
// ---------------------------------------------------------------------------
__global__ void __launch_bounds__(256) k_splat(const float4* __restrict__ pts,
                                               float* __restrict__ hs, int N) {
    extern __shared__ float tile[];         // F_ * 64 floats = 64 KB
    int seg = blockIdx.x >> 5;              // 0..3
    int b   = blockIdx.x & 31;
    for (int t = threadIdx.x; t < F_ * 64; t += 256) tile[t] = 0.0f;
    __syncthreads();

    int ylo = seg * 64;
    int nq = N >> 1;                        // float4 = 2 points
    const float4* p = pts + (size_t)b * nq;
    for (int t = threadIdx.x; t < nq; t += 256) {
        float4 q = p[t];
#pragma unroll
        for (int h = 0; h < 2; h++) {
            float bx = h ? q.z : q.x;
            float dy = h ? q.w : q.y;
            float pers = fminf(fabsf(dy - bx), 10.0f);
            float wgt = pers * pers;
            float fx = fminf(fmaxf(bx * 255.0f, 0.0f), 255.0f);
            float fy = fminf(fmaxf(dy * 255.0f, 0.0f), 255.0f);
            int ix = (int)fx; if (ix > 254) ix = 254;
            int iy = (int)fy; if (iy > 254) iy = 254;
            float ax = fx - (float)ix;
            float ay = fy - (float)iy;
            int cy0 = iy - ylo;
            float wx0 = wgt * (1.0f - ax), wx1 = wgt * ax;
            int o0 = (ix << 6) + cy0;
            if ((unsigned)cy0 < 64u) {
                float a0 = 1.0f - ay;
                atomicAdd(&tile[o0],      wx0 * a0);
                atomicAdd(&tile[o0 + 64], wx1 * a0);
            }
            if ((unsigned)(cy0 + 1) < 64u) {
                atomicAdd(&tile[o0 + 1],  wx0 * ay);
                atomicAdd(&tile[o0 + 65], wx1 * ay);
            }
        }
    }
    __syncthreads();

    float* dst = hs + (size_t)b * (F_ * F_) + ylo;
    for (int t = threadIdx.x; t < F_ * 64; t += 256)
        dst[(size_t)(t >> 6) * F_ + (t & 63)] = tile[t];
}

// ---------------------------------------------------------------------------
// K2: T[b][i][cy] = sum_cx gtab[cx][i] * hs[b][cx][cy]
//     Block = (b, cyChunk of 64). 256 thr = 64 cy-lanes x 4 waves; wave ty
//     owns rows i = ty*13+k. gtab staged in LDS; per cx: 3x ds_read_b128 + 1
//     wave-uniform broadcast + coalesced h load + 13 FMA. Rows 50,51 are 0
//     (zero table slots) and stored unguarded into the 52-row padded T.
// ---------------------------------------------------------------------------
__global__ void __launch_bounds__(256) k_conv1(const float* __restrict__ gtab,
                                               const float* __restrict__ hs,
                                               float* __restrict__ T) {
    extern __shared__ float sg[];           // 16384 floats = 64 KB
    for (int t = threadIdx.x; t < F_ * 64; t += 256) sg[t] = gtab[t];
    __syncthreads();

    int cyc = blockIdx.x & 3;
    int b   = blockIdx.x >> 2;
    int tx = threadIdx.x & 63, ty = threadIdx.x >> 6;
    int cy = cyc * 64 + tx;
    int gb = ty * 16;

    float acc[13];
#pragma unroll
    for (int k = 0; k < 13; k++) acc[k] = 0.0f;

    const float* hsb = hs + (size_t)b * (F_ * F_) + cy;
#pragma unroll 4
    for (int cx = 0; cx < F_; cx++) {
        float h = hsb[(size_t)cx * F_];
        const float* g = &sg[cx * 64 + gb];
        float4 g0 = *(const float4*)(g);
        float4 g1 = *(const float4*)(g + 4);
        float4 g2 = *(const float4*)(g + 8);
        float  gc = g[12];
        acc[0]  += g0.x * h;  acc[1]  += g0.y * h;
        acc[2]  += g0.z * h;  acc[3]  += g0.w * h;
        acc[4]  += g1.x * h;  acc[5]  += g1.y * h;
        acc[6]  += g1.z * h;  acc[7]  += g1.w * h;
        acc[8]  += g2.x * h;  acc[9]  += g2.y * h;
        acc[10] += g2.z * h;  acc[11] += g2.w * h;
        acc[12] += gc * h;
    }

    float* Tp = T + ((size_t)b * 52 + (size_t)ty * 13) * F_ + cy;
#pragma unroll
    for (int k = 0; k < 13; k++) Tp[(size_t)k * F_] = acc[k];
}

// ---------------------------------------------------------------------------
// K3: out[b][i][j] = sum_cy T[b][i][cy] * gtab[cy][j]
//     Block = (b, q); rows i = q*13+k. T rows staged in LDS (broadcast
//     reads); each of 4 waves reduces a 64-cy quarter; LDS tree reduce.
// ---------------------------------------------------------------------------
__global__ void __launch_bounds__(256) k_conv2(const float* __restrict__ gtab,
                                               const float* __restrict__ T,
                                               float* __restrict__ out) {
    __shared__ float sT[13 * 256];          // 13 KB, reused as red[4][13][64]
    int q = blockIdx.x & 3;
    int b = blockIdx.x >> 2;

    const float* Tq = T + ((size_t)b * 52 + (size_t)q * 13) * F_;
    for (int t = threadIdx.x; t < 13 * 256; t += 256) sT[t] = Tq[t];
    __syncthreads();

    int j = threadIdx.x & 63;
    int w = threadIdx.x >> 6;
    int jc = j < RES_ ? j : RES_ - 1;
    int jo = (jc / 13) * 16 + (jc % 13);    // padded-slot column for output j

    float acc[13];
#pragma unroll
    for (int k = 0; k < 13; k++) acc[k] = 0.0f;

    const float* gp = gtab + jo + (size_t)w * 64 * 64;
    int cyb = w * 64;
#pragma unroll 4
    for (int c = 0; c < 64; c++) {
        float g = gp[(size_t)c * 64];
#pragma unroll
        for (int k = 0; k < 13; k++) acc[k] += sT[k * 256 + cyb + c] * g;
    }
    __syncthreads();

#pragma unroll
    for (int k = 0; k < 13; k++) sT[(w * 13 + k) * 64 + j] = acc[k];
    __syncthreads();

    for (int t = threadIdx.x; t < 13 * 64; t += 256) {
        int k = t >> 6, jj = t & 63;
        int i = q * 13 + k;
        if (i < RES_ && jj < RES_) {
            float s = sT[(0 * 13 + k) * 64 + jj] + sT[(1 * 13 + k) * 64 + jj]
                    + sT[(2 * 13 + k) * 64 + jj] + sT[(3 * 13 + k) * 64 + jj];
            out[((size_t)b * RES_ + i) * RES_ + jj] = s;
        }
    }
}

// ---------------------------------------------------------------------------
extern "C" void kernel_launch(void* const* d_in, const int* in_sizes, int n_in,
                              void* d_out, int out_size, void* d_ws, size_t ws_size,
                              hipStream_t stream) {
    const float4* pts = (const float4*)d_in[0];
    int N = in_sizes[0] / (2 * B_);         // 65536
    float* ws = (float*)d_ws;
    float* out = (float*)d_out;

    float* gtab = ws;                       // 16,384 floats (64 KB)
    float* hs   = gtab + F_ * 64;           // 32*256*256 = 2,097,152 floats
    float* T    = hs + (size_t)B_ * F_ * F_; // 32*52*256 = 425,984 floats
                                            // total ~10.2 MB << ws (>=44 MB proven)

    k_tables<<<F_, 64, 0, stream>>>(gtab);
    k_splat<<<128, 256, (size_t)F_ * 64 * 4, stream>>>(pts, hs, N);
    k_conv1<<<128, 256, (size_t)F_ * 64 * 4, stream>>>(gtab, hs, T);
    k_conv2<<<128, 256, 0, stream>>>(gtab, T, out);
}